// Round 7
// baseline (67.118 us; speedup 1.0000x reference)
//
#include <hip/hip_runtime.h>
#include <hip/hip_bf16.h>

typedef __fp16 h2   __attribute__((ext_vector_type(2)));
typedef __fp16 v8h  __attribute__((ext_vector_type(8)));
typedef _Float16 v8f16 __attribute__((ext_vector_type(8)));
typedef float  v16f __attribute__((ext_vector_type(16)));

#define NT 5                      // n-tiles (160 cols: 136 real + 24 pad)
#define KTSTRIDE (NT * 64 * 8)    // shorts per kt slice = 2560

__device__ __forceinline__ short h16(float f) {
    return __builtin_bit_cast(short, (_Float16)f);   // RNE f32->f16
}

__device__ __forceinline__ void gload16(const short* g, short* l) {
    __builtin_amdgcn_global_load_lds(
        (const __attribute__((address_space(1))) unsigned int*)g,
        (__attribute__((address_space(3))) unsigned int*)l, 16, 0, 0);
}

__device__ __forceinline__ v8h pack4(h2 a, h2 b, h2 c, h2 d) {
    union { int4 i; v8h h; } u;
    u.i = make_int4(__builtin_bit_cast(int, a), __builtin_bit_cast(int, b),
                    __builtin_bit_cast(int, c), __builtin_bit_cast(int, d));
    return u.h;
}

__device__ __forceinline__ v16f mfma_f16(v8h a, v8h b, v16f c) {
    return __builtin_amdgcn_mfma_f32_32x32x16_f16(
        __builtin_bit_cast(v8f16, a), __builtin_bit_cast(v8f16, b), c, 0, 0, 0);
}

__device__ __forceinline__ int slotof(int i) { return ((i & 1) << 3) | (i >> 1); }

// ---------------------------------------------------------------------------
// Prep: symmetrized U3/U2 -> fragment-ordered fp16 B (N=160 tri-packed cols).
//   col n < 136 <-> (p<=q); Usym = U[p,q] + (p!=q ? U[q,p] : 0).
// Layout: Bg[kt(12)][nt(5)][lane(64)][j(8)] u16, kt stride 2560.
//   kt<11: B[k3,i-slice]; kt=11: U2sym at h=0, j=k2<4.
// Appended: int tbl[160] = slot(p) | slot(q)<<8 at Bg+12*2560 shorts.
// ---------------------------------------------------------------------------
__global__ void symcon_prep(const float* __restrict__ U3, const float* __restrict__ U2,
                            short* __restrict__ Bg)
{
    const int g = blockIdx.x * 256 + threadIdx.x;   // 0..2559
    if (g >= 160 * 16) return;
    const int n = g >> 4;                           // column 0..159
    const int i = g & 15;
    const int nt = n >> 5, lb = n & 31;
    const int lane = lb | ((i >> 3) << 5), j = i & 7;
    int* tblp = (int*)(Bg + 12 * KTSTRIDE);
    short* dst = Bg + (nt * 64 + lane) * 8 + j;
    if (n < 136) {
        int p = 0, base = 0;
        while (base + (16 - p) <= n) { base += 16 - p; ++p; }
        const int q = p + (n - base);
        const float* up = U3 + ((p * 16 + q) * 16 + i) * 11;
        const float* uq = U3 + ((q * 16 + p) * 16 + i) * 11;
        #pragma unroll
        for (int k3 = 0; k3 < 11; ++k3)
            dst[k3 * KTSTRIDE] = h16(up[k3] + (p != q ? uq[k3] : 0.f));
        if (i == 0) {
            short* d0 = Bg + 11 * KTSTRIDE + (nt * 64 + lb) * 8;
            #pragma unroll
            for (int jj = 0; jj < 4; ++jj)
                d0[jj] = h16(U2[(p * 16 + q) * 4 + jj] + (p != q ? U2[(q * 16 + p) * 4 + jj] : 0.f));
            #pragma unroll
            for (int jj = 4; jj < 8; ++jj) d0[jj] = 0;
            short* d1 = Bg + 11 * KTSTRIDE + (nt * 64 + lb + 32) * 8;
            #pragma unroll
            for (int jj = 0; jj < 8; ++jj) d1[jj] = 0;
            tblp[n] = slotof(p) | (slotof(q) << 8);
        }
    } else {
        #pragma unroll
        for (int k3 = 0; k3 < 11; ++k3) dst[k3 * KTSTRIDE] = 0;
        if (i == 0) {
            short* d0 = Bg + 11 * KTSTRIDE + (nt * 64 + lb) * 8;
            short* d1 = Bg + 11 * KTSTRIDE + (nt * 64 + lb + 32) * 8;
            #pragma unroll
            for (int jj = 0; jj < 8; ++jj) { d0[jj] = 0; d1[jj] = 0; }
            tblp[n] = 0;
        }
    }
}

// ---------------------------------------------------------------------------
// Main: 1 node per 640-thread block; 10 waves = 2(M-halves) x 5(N-tiles).
// Per wave: 64 rows x 32 cols -> acc = 2 x v16f (32 regs). fp16 GEMM K=192,
// B LDS-staged (dbuf, counted vmcnt, pinned). Tri-packed symmetric epilogue.
// ---------------------------------------------------------------------------
__global__ __launch_bounds__(640, 5)
void symcon_main(const float* __restrict__ x, const float* __restrict__ y,
                 const float* __restrict__ U1, const float* __restrict__ W3,
                 const float* __restrict__ W2, const float* __restrict__ W1,
                 const short* __restrict__ Bg, float* __restrict__ out)
{
    __shared__ __align__(16) short Bl[2][2][KTSTRIDE];  // 20 KB
    __shared__ __align__(16) float x_re[128][16];       // 8 KB
    __shared__ __align__(16) float Sbuf[128][40];       // 20 KB
    __shared__ __align__(16) float u1l[16];

    const int tid  = threadIdx.x;
    const int node = blockIdx.x;
    const int lane = tid & 63;
    const int wid  = tid >> 6;            // 0..9
    const int mw   = (wid < 5) ? 0 : 1;   // M half
    const int nt   = wid - mw * 5;        // N tile 0..4
    const int col  = lane & 31;
    const int h    = lane >> 5;
    const int rbA  = mw * 64 + col;

    // ---- prologue staging: phases 0 {kt11,kt0} and 1 {kt1,kt2} ----
    {
        const int sub = (tid >= 320);
        const int off = (tid - sub * 320) * 8;
        gload16(Bg + (sub ? 0 : 11) * KTSTRIDE + off, &Bl[0][sub][off]);
        gload16(Bg + (1 + sub) * KTSTRIDE + off, &Bl[1][sub][off]);
    }

    // ---- species (argmax, first-max wins) ----
    int e = 0;
    {
        const float* yr = y + node * 10;
        float best = yr[0];
        #pragma unroll
        for (int s2 = 1; s2 < 10; ++s2) { const float v = yr[s2]; if (v > best) { best = v; e = s2; } }
    }

    // ---- stage permuted x tile: x_re[r][(i&1)*8 + (i>>1)] = x[r][i] ----
    if (tid < 512) {
        const int r = tid >> 2, seg = tid & 3;
        const float4 v = *reinterpret_cast<const float4*>(x + ((size_t)node * 128 + r) * 16 + seg * 4);
        *reinterpret_cast<float2*>(&x_re[r][2 * seg])     = make_float2(v.x, v.z);
        *reinterpret_cast<float2*>(&x_re[r][8 + 2 * seg]) = make_float2(v.y, v.w);
    }
    if (tid < 16) u1l[tid] = U1[2 * (tid & 7) + (tid >> 3)];

    // ---- per-lane weights + epilogue table + W1 (early, hide latency) ----
    float w3a[11], w3b[11], w2a[4], w2b[4];
    #pragma unroll
    for (int k = 0; k < 11; ++k) {
        w3a[k] = W3[(e * 11 + k) * 128 + rbA];
        w3b[k] = W3[(e * 11 + k) * 128 + rbA + 32];
    }
    #pragma unroll
    for (int k = 0; k < 4; ++k) {
        w2a[k] = W2[(e * 4 + k) * 128 + rbA];
        w2b[k] = W2[(e * 4 + k) * 128 + rbA + 32];
    }
    const int tb = ((const int*)(Bg + 12 * KTSTRIDE))[nt * 32 + col];
    const int ps = tb & 255, qs = (tb >> 8) & 255;
    const float w1v = (tid < 512) ? W1[e * 128 + (tid >> 2)] : 0.f;

    __syncthreads();   // x_re ready (also drains prologue vmcnt)

    // ---- x as packed half2 ----
    h2 xh0[4], xh1[4];
    {
        const float4 e0 = *reinterpret_cast<const float4*>(&x_re[rbA][4 * h]);
        const float4 o0 = *reinterpret_cast<const float4*>(&x_re[rbA][8 + 4 * h]);
        const float4 e1 = *reinterpret_cast<const float4*>(&x_re[rbA + 32][4 * h]);
        const float4 o1 = *reinterpret_cast<const float4*>(&x_re[rbA + 32][8 + 4 * h]);
        xh0[0] = h2{(__fp16)e0.x, (__fp16)o0.x};
        xh0[1] = h2{(__fp16)e0.y, (__fp16)o0.y};
        xh0[2] = h2{(__fp16)e0.z, (__fp16)o0.z};
        xh0[3] = h2{(__fp16)e0.w, (__fp16)o0.w};
        xh1[0] = h2{(__fp16)e1.x, (__fp16)o1.x};
        xh1[1] = h2{(__fp16)e1.y, (__fp16)o1.y};
        xh1[2] = h2{(__fp16)e1.z, (__fp16)o1.z};
        xh1[3] = h2{(__fp16)e1.w, (__fp16)o1.w};
    }

    v16f acc0 = {}, acc1 = {};

    // ---- K loop: 6 phases x 2 kt; per-thread 1 restage/phase ----
    #pragma unroll
    for (int s = 0; s < 6; ++s) {
        if (s == 5) { asm volatile("s_waitcnt vmcnt(0)" ::: "memory"); }
        else        { asm volatile("s_waitcnt vmcnt(1)" ::: "memory"); }
        __builtin_amdgcn_s_barrier();
        __builtin_amdgcn_sched_barrier(0);

        #pragma unroll
        for (int u = 0; u < 2; ++u) {
            const v8h bf = *reinterpret_cast<const v8h*>(&Bl[s & 1][u][(nt * 64 + lane) * 8]);
            v8h a0, a1;
            if (s == 0 && u == 0) {
                const h2 z = {};
                const h2 p00 = h ? z : h2{(__fp16)w2a[0], (__fp16)w2a[1]};
                const h2 p01 = h ? z : h2{(__fp16)w2a[2], (__fp16)w2a[3]};
                const h2 p10 = h ? z : h2{(__fp16)w2b[0], (__fp16)w2b[1]};
                const h2 p11 = h ? z : h2{(__fp16)w2b[2], (__fp16)w2b[3]};
                a0 = pack4(p00, p01, z, z);
                a1 = pack4(p10, p11, z, z);
            } else {
                const int kt = (s == 0) ? 0 : (2 * s - 1 + u);
                const __fp16 wha = (__fp16)w3a[kt];
                const __fp16 whb = (__fp16)w3b[kt];
                const h2 wa = h2{wha, wha};
                const h2 wb = h2{whb, whb};
                a0 = pack4(xh0[0] * wa, xh0[1] * wa, xh0[2] * wa, xh0[3] * wa);
                a1 = pack4(xh1[0] * wb, xh1[1] * wb, xh1[2] * wb, xh1[3] * wb);
            }
            acc0 = mfma_f16(a0, bf, acc0);
            acc1 = mfma_f16(a1, bf, acc1);
        }

        __builtin_amdgcn_sched_barrier(0);
        __builtin_amdgcn_s_barrier();
        if (s < 4) {   // stage phase s+2 = kts {2s+3, 2s+4}
            const int sub = (tid >= 320);
            const int off = (tid - sub * 320) * 8;
            gload16(Bg + (2 * s + 3 + sub) * KTSTRIDE + off, &Bl[s & 1][sub][off]);
        }
    }

    // ---- epilogue: s = D[m,n] * x_p(n) * x_q(n), fold 32 cols -> 8 ----
    #pragma unroll
    for (int mr = 0; mr < 2; ++mr) {
        #pragma unroll
        for (int rg = 0; rg < 16; ++rg) {
            const int row = mw * 64 + mr * 32 + (rg & 3) + ((rg >> 2) << 3) + 4 * h;
            const float d = mr ? acc1[rg] : acc0[rg];
            float s = d * x_re[row][ps] * x_re[row][qs];
            s += __shfl_xor(s, 16);
            s += __shfl_xor(s, 8);
            if (col < 8) Sbuf[row][nt * 8 + col] = s;
        }
    }

    __syncthreads();   // Sbuf complete

    // ---- final: 4 lanes per row reduce Sbuf(40) + U1 term ----
    if (tid < 512) {
        const int r = tid >> 2, g = tid & 3;
        const float4 xv = *reinterpret_cast<const float4*>(&x_re[r][g * 4]);
        const float4 uv = *reinterpret_cast<const float4*>(&u1l[g * 4]);
        float s = w1v * (xv.x * uv.x + xv.y * uv.y + xv.z * uv.z + xv.w * uv.w);
        #pragma unroll
        for (int jj = 0; jj < 10; ++jj) s += Sbuf[r][g + 4 * jj];
        s += __shfl_xor(s, 1);
        s += __shfl_xor(s, 2);
        if (g == 0) out[(size_t)node * 128 + r] = s;
    }
}

extern "C" void kernel_launch(void* const* d_in, const int* in_sizes, int n_in,
                              void* d_out, int out_size, void* d_ws, size_t ws_size,
                              hipStream_t stream) {
    const float* x  = (const float*)d_in[0];
    const float* y  = (const float*)d_in[1];
    const float* U3 = (const float*)d_in[2];
    const float* U2 = (const float*)d_in[3];
    const float* U1 = (const float*)d_in[4];
    const float* W3 = (const float*)d_in[5];
    const float* W2 = (const float*)d_in[6];
    const float* W1 = (const float*)d_in[7];
    short* Bg = (short*)d_ws;   // 12*2560 shorts + 160 ints = 62 KB

    symcon_prep<<<10, 256, 0, stream>>>(U3, U2, Bg);
    symcon_main<<<2048, 640, 0, stream>>>(x, y, U1, W3, W2, W1, Bg, (float*)d_out);
}

// Round 8
// 32.741 us; speedup vs baseline: 2.0500x; 2.0500x over previous
//
#include <hip/hip_runtime.h>
#include <hip/hip_bf16.h>
#include <utility>

typedef __fp16 h2    __attribute__((ext_vector_type(2)));
typedef __fp16 v8h   __attribute__((ext_vector_type(8)));
typedef _Float16 v8f16 __attribute__((ext_vector_type(8)));
typedef float  v4f   __attribute__((ext_vector_type(4)));
typedef float  v16f  __attribute__((ext_vector_type(16)));

#define NT 5                      // n-tiles (160 cols: 136 real + 24 pad)
#define KTSTRIDE (NT * 64 * 8)    // shorts per kt slice = 2560

__device__ __forceinline__ short h16(float f) {
    return __builtin_bit_cast(short, (_Float16)f);   // RNE f32->f16
}

__device__ __forceinline__ v8h pack4(h2 a, h2 b, h2 c, h2 d) {
    union { int4 i; v8h h; } u;
    u.i = make_int4(__builtin_bit_cast(int, a), __builtin_bit_cast(int, b),
                    __builtin_bit_cast(int, c), __builtin_bit_cast(int, d));
    return u.h;
}

__device__ __forceinline__ v16f mfma_f16(v8h a, v8h b, v16f c) {
    return __builtin_amdgcn_mfma_f32_32x32x16_f16(
        __builtin_bit_cast(v8f16, a), __builtin_bit_cast(v8f16, b), c, 0, 0, 0);
}

// tri-pack mapping: col n (0..135) <-> (p<=q)
constexpr int pof(int n) {
    int p = 0, b = 0;
    while (b + (16 - p) <= n) { b += 16 - p; ++p; }
    return p;
}
constexpr int qof(int n) {
    int p = 0, b = 0;
    while (b + (16 - p) <= n) { b += 16 - p; ++p; }
    return p + (n - b);
}

// compile-time component extract from 4x v4f (registers, no dynamic index)
template<int I>
__device__ __forceinline__ float xi(v4f f0, v4f f1, v4f f2, v4f f3) {
    if constexpr (I < 4)       return f0[I];
    else if constexpr (I < 8)  return f1[I - 4];
    else if constexpr (I < 12) return f2[I - 8];
    else                       return f3[I - 12];
}

template<int N>
__device__ __forceinline__ float gg(v4f f0, v4f f1, v4f f2, v4f f3) {
    if constexpr (N >= 136) return 0.f;
    else return xi<pof(N)>(f0, f1, f2, f3) * xi<qof(N)>(f0, f1, f2, f3);
}

// epilogue for one n-tile: s = sum_rg acc[rg] * x_p(n)*x_q(n), n = NTI*32 + row(rg,h)
template<int NTI, int... RG>
__device__ __forceinline__ float epi_impl(const v16f& a, v4f f0, v4f f1, v4f f2, v4f f3,
                                          int h, std::integer_sequence<int, RG...>) {
    float s = 0.f;
    ((s = fmaf(a[RG],
               h ? gg<NTI * 32 + (RG & 3) + 8 * (RG >> 2) + 4>(f0, f1, f2, f3)
                 : gg<NTI * 32 + (RG & 3) + 8 * (RG >> 2)>(f0, f1, f2, f3),
               s)), ...);
    return s;
}
template<int NTI>
__device__ __forceinline__ float epi(const v16f& a, v4f f0, v4f f1, v4f f2, v4f f3, int h) {
    return epi_impl<NTI>(a, f0, f1, f2, f3, h, std::make_integer_sequence<int, 16>{});
}

// ---------------------------------------------------------------------------
// Prep: symmetrized U3/U2 -> fragment-ordered fp16 A-matrix (tri-packed n rows).
// Layout: Bg[kt(12)][nt(5)][lane(64)][j(8)] u16; at lane: n = lane&31 (+nt*32),
// i = 8*(lane>>5) + j. kt=11: U2sym at h=0, j=k2<4, rest zero.
// ---------------------------------------------------------------------------
__global__ void symcon_prep(const float* __restrict__ U3, const float* __restrict__ U2,
                            short* __restrict__ Bg)
{
    const int g = blockIdx.x * 256 + threadIdx.x;   // 0..2559
    if (g >= 160 * 16) return;
    const int n = g >> 4;                           // column 0..159
    const int i = g & 15;
    const int nt = n >> 5, lb = n & 31;
    const int lane = lb | ((i >> 3) << 5), j = i & 7;
    short* dst = Bg + (nt * 64 + lane) * 8 + j;
    if (n < 136) {
        int p = 0, base = 0;
        while (base + (16 - p) <= n) { base += 16 - p; ++p; }
        const int q = p + (n - base);
        const float* up = U3 + ((p * 16 + q) * 16 + i) * 11;
        const float* uq = U3 + ((q * 16 + p) * 16 + i) * 11;
        #pragma unroll
        for (int k3 = 0; k3 < 11; ++k3)
            dst[k3 * KTSTRIDE] = h16(up[k3] + (p != q ? uq[k3] : 0.f));
        if (i == 0) {
            short* d0 = Bg + 11 * KTSTRIDE + (nt * 64 + lb) * 8;
            #pragma unroll
            for (int jj = 0; jj < 4; ++jj)
                d0[jj] = h16(U2[(p * 16 + q) * 4 + jj] + (p != q ? U2[(q * 16 + p) * 4 + jj] : 0.f));
            #pragma unroll
            for (int jj = 4; jj < 8; ++jj) d0[jj] = 0;
            short* d1 = Bg + 11 * KTSTRIDE + (nt * 64 + lb + 32) * 8;
            #pragma unroll
            for (int jj = 0; jj < 8; ++jj) d1[jj] = 0;
        }
    } else {
        #pragma unroll
        for (int k3 = 0; k3 < 11; ++k3) dst[k3 * KTSTRIDE] = 0;
        if (i == 0) {
            short* d0 = Bg + 11 * KTSTRIDE + (nt * 64 + lb) * 8;
            short* d1 = Bg + 11 * KTSTRIDE + (nt * 64 + lb + 32) * 8;
            #pragma unroll
            for (int jj = 0; jj < 8; ++jj) { d0[jj] = 0; d1[jj] = 0; }
        }
    }
}

// ---------------------------------------------------------------------------
// Main: 1 wave per block (64 threads), 32 output rows (m = channel slice).
// Swapped GEMM: D^T[n, m] = Usym[n, k] . z[k, m],  z[k3*16+i, m] = x[m,i]*w3[m,k3].
// Lane owns m = lane&31: its x, its weights, and (via C/D col=lane) its full
// D row -> register-only quadratic epilogue. NO LDS, NO barriers anywhere.
// ---------------------------------------------------------------------------
__global__ __launch_bounds__(64, 3)
void symcon_main(const float* __restrict__ x, const float* __restrict__ y,
                 const float* __restrict__ U1, const float* __restrict__ W3,
                 const float* __restrict__ W2, const float* __restrict__ W1,
                 const short* __restrict__ Bg, float* __restrict__ out)
{
    const int bid  = blockIdx.x;
    const int node = bid >> 2;
    const int wr   = bid & 3;
    const int lane = threadIdx.x;
    const int col  = lane & 31;
    const int h    = lane >> 5;
    const int m    = wr * 32 + col;          // channel (output row) this lane owns

    // ---- x row (16 floats) ----
    const float* xp = x + ((size_t)node * 128 + m) * 16;
    const v4f f0 = *reinterpret_cast<const v4f*>(xp);
    const v4f f1 = *reinterpret_cast<const v4f*>(xp + 4);
    const v4f f2 = *reinterpret_cast<const v4f*>(xp + 8);
    const v4f f3 = *reinterpret_cast<const v4f*>(xp + 12);

    // ---- species (argmax, first-max wins) ----
    int e = 0;
    {
        const float* yr = y + node * 10;
        float best = yr[0];
        #pragma unroll
        for (int s2 = 1; s2 < 10; ++s2) { const float v = yr[s2]; if (v > best) { best = v; e = s2; } }
    }

    // ---- U1 dot (lane-local) ----
    float u1dot;
    {
        const v4f u0 = *reinterpret_cast<const v4f*>(U1);
        const v4f u1 = *reinterpret_cast<const v4f*>(U1 + 4);
        const v4f u2 = *reinterpret_cast<const v4f*>(U1 + 8);
        const v4f u3 = *reinterpret_cast<const v4f*>(U1 + 12);
        const v4f d  = f0 * u0 + f1 * u1 + f2 * u2 + f3 * u3;
        u1dot = d[0] + d[1] + d[2] + d[3];
    }

    // ---- per-lane weights (e-dependent gather, coalesced 32-lane rows) ----
    float w3r[11], w2r[4];
    #pragma unroll
    for (int k = 0; k < 11; ++k) w3r[k] = W3[(e * 11 + k) * 128 + m];
    #pragma unroll
    for (int k = 0; k < 4; ++k)  w2r[k] = W2[(e * 4 + k) * 128 + m];
    const float w1v = W1[e * 128 + m];

    // ---- lane's x half as packed fp16 (RNE): z k-elements 8h..8h+7 ----
    const v4f lo = h ? f2 : f0;
    const v4f hi = h ? f3 : f1;
    const h2 xh0 = h2{(__fp16)lo[0], (__fp16)lo[1]};
    const h2 xh1 = h2{(__fp16)lo[2], (__fp16)lo[3]};
    const h2 xh2 = h2{(__fp16)hi[0], (__fp16)hi[1]};
    const h2 xh3 = h2{(__fp16)hi[2], (__fp16)hi[3]};

    v16f a0 = {}, a1 = {}, a2 = {}, a3 = {}, a4 = {};

    // ---- K loop: 12 kt, 5 n-tiles; U frags from L1/L2, B built in-register ----
    const short* Up = Bg + lane * 8;
    #pragma unroll
    for (int kt = 0; kt < 12; ++kt) {
        const v8h u0 = *reinterpret_cast<const v8h*>(Up + (kt * NT + 0) * 512);
        const v8h u1 = *reinterpret_cast<const v8h*>(Up + (kt * NT + 1) * 512);
        const v8h u2 = *reinterpret_cast<const v8h*>(Up + (kt * NT + 2) * 512);
        const v8h u3 = *reinterpret_cast<const v8h*>(Up + (kt * NT + 3) * 512);
        const v8h u4 = *reinterpret_cast<const v8h*>(Up + (kt * NT + 4) * 512);
        v8h b;
        if (kt < 11) {
            const __fp16 w = (__fp16)w3r[kt];
            const h2 wh = h2{w, w};
            b = pack4(xh0 * wh, xh1 * wh, xh2 * wh, xh3 * wh);
        } else {
            const h2 z = {};
            const h2 p0 = h ? z : h2{(__fp16)w2r[0], (__fp16)w2r[1]};
            const h2 p1 = h ? z : h2{(__fp16)w2r[2], (__fp16)w2r[3]};
            b = pack4(p0, p1, z, z);
        }
        a0 = mfma_f16(u0, b, a0);
        a1 = mfma_f16(u1, b, a1);
        a2 = mfma_f16(u2, b, a2);
        a3 = mfma_f16(u3, b, a3);
        a4 = mfma_f16(u4, b, a4);
    }

    // ---- register-only epilogue: s = sum_n D[m,n] * x_p(n) * x_q(n) ----
    float s = epi<0>(a0, f0, f1, f2, f3, h)
            + epi<1>(a1, f0, f1, f2, f3, h)
            + epi<2>(a2, f0, f1, f2, f3, h)
            + epi<3>(a3, f0, f1, f2, f3, h)
            + epi<4>(a4, f0, f1, f2, f3, h);

    s += __shfl_xor(s, 32);   // combine h=0/h=1 n-halves (same m)

    if (h == 0)
        out[(size_t)node * 128 + m] = s + w1v * u1dot;
}

extern "C" void kernel_launch(void* const* d_in, const int* in_sizes, int n_in,
                              void* d_out, int out_size, void* d_ws, size_t ws_size,
                              hipStream_t stream) {
    const float* x  = (const float*)d_in[0];
    const float* y  = (const float*)d_in[1];
    const float* U3 = (const float*)d_in[2];
    const float* U2 = (const float*)d_in[3];
    const float* U1 = (const float*)d_in[4];
    const float* W3 = (const float*)d_in[5];
    const float* W2 = (const float*)d_in[6];
    const float* W1 = (const float*)d_in[7];
    short* Bg = (short*)d_ws;   // 12*2560 shorts = 60 KB fp16 Usym

    symcon_prep<<<10, 256, 0, stream>>>(U3, U2, Bg);
    symcon_main<<<8192, 64, 0, stream>>>(x, y, U1, W3, W2, W1, Bg, (float*)d_out);
}

// Round 9
// 26.973 us; speedup vs baseline: 2.4883x; 1.2138x over previous
//
#include <hip/hip_runtime.h>
#include <hip/hip_bf16.h>
#include <utility>

typedef __fp16 h2    __attribute__((ext_vector_type(2)));
typedef __fp16 v8h   __attribute__((ext_vector_type(8)));
typedef _Float16 v8f16 __attribute__((ext_vector_type(8)));
typedef float  v4f   __attribute__((ext_vector_type(4)));
typedef float  v16f  __attribute__((ext_vector_type(16)));

#define NT 5                      // n-tiles (160 cols: 136 real + 24 pad)
#define KTSTRIDE (NT * 64 * 8)    // shorts per kt slice = 2560
#define NCHUNK (12 * NT * 64)     // 16B chunks in U = 3840

__device__ __forceinline__ short h16(float f) {
    return __builtin_bit_cast(short, (_Float16)f);   // RNE f32->f16
}

__device__ __forceinline__ void gload16(const short* g, short* l) {
    __builtin_amdgcn_global_load_lds(
        (const __attribute__((address_space(1))) unsigned int*)g,
        (__attribute__((address_space(3))) unsigned int*)l, 16, 0, 0);
}

__device__ __forceinline__ v8h pack4(h2 a, h2 b, h2 c, h2 d) {
    union { int4 i; v8h h; } u;
    u.i = make_int4(__builtin_bit_cast(int, a), __builtin_bit_cast(int, b),
                    __builtin_bit_cast(int, c), __builtin_bit_cast(int, d));
    return u.h;
}

__device__ __forceinline__ v16f mfma_f16(v8h a, v8h b, v16f c) {
    return __builtin_amdgcn_mfma_f32_32x32x16_f16(
        __builtin_bit_cast(v8f16, a), __builtin_bit_cast(v8f16, b), c, 0, 0, 0);
}

// tri-pack mapping: col n (0..135) <-> (p<=q)
constexpr int pof(int n) {
    int p = 0, b = 0;
    while (b + (16 - p) <= n) { b += 16 - p; ++p; }
    return p;
}
constexpr int qof(int n) {
    int p = 0, b = 0;
    while (b + (16 - p) <= n) { b += 16 - p; ++p; }
    return p + (n - b);
}

// compile-time component extract from 4x v4f (registers, no dynamic index)
template<int I>
__device__ __forceinline__ float xi(v4f f0, v4f f1, v4f f2, v4f f3) {
    if constexpr (I < 4)       return f0[I];
    else if constexpr (I < 8)  return f1[I - 4];
    else if constexpr (I < 12) return f2[I - 8];
    else                       return f3[I - 12];
}

template<int N>
__device__ __forceinline__ float gg(v4f f0, v4f f1, v4f f2, v4f f3) {
    if constexpr (N >= 136) return 0.f;
    else return xi<pof(N)>(f0, f1, f2, f3) * xi<qof(N)>(f0, f1, f2, f3);
}

// epilogue for one n-tile: s += acc[rg] * x_p(n)*x_q(n), n = NTI*32 + row(rg,h)
template<int NTI, int... RG>
__device__ __forceinline__ float epi_impl(const v16f& a, v4f f0, v4f f1, v4f f2, v4f f3,
                                          int h, std::integer_sequence<int, RG...>) {
    float s = 0.f;
    ((s = fmaf(a[RG],
               h ? gg<NTI * 32 + (RG & 3) + 8 * (RG >> 2) + 4>(f0, f1, f2, f3)
                 : gg<NTI * 32 + (RG & 3) + 8 * (RG >> 2)>(f0, f1, f2, f3),
               s)), ...);
    return s;
}
template<int NTI>
__device__ __forceinline__ float epi(const v16f& a, v4f f0, v4f f1, v4f f2, v4f f3, int h) {
    return epi_impl<NTI>(a, f0, f1, f2, f3, h, std::make_integer_sequence<int, 16>{});
}

// ---------------------------------------------------------------------------
// Prep: symmetrized U3/U2 -> fragment-ordered fp16 A-matrix (tri-packed n rows).
// Layout: Bg[kt(12)][nt(5)][lane(64)][j(8)] u16; at lane: n = lane&31 (+nt*32),
// i = 8*(lane>>5) + j. kt=11: U2sym at h=0, j=k2<4, rest zero.
// ---------------------------------------------------------------------------
__global__ void symcon_prep(const float* __restrict__ U3, const float* __restrict__ U2,
                            short* __restrict__ Bg)
{
    const int g = blockIdx.x * 256 + threadIdx.x;   // 0..2559
    if (g >= 160 * 16) return;
    const int n = g >> 4;                           // column 0..159
    const int i = g & 15;
    const int nt = n >> 5, lb = n & 31;
    const int lane = lb | ((i >> 3) << 5), j = i & 7;
    short* dst = Bg + (nt * 64 + lane) * 8 + j;
    if (n < 136) {
        int p = 0, base = 0;
        while (base + (16 - p) <= n) { base += 16 - p; ++p; }
        const int q = p + (n - base);
        const float* up = U3 + ((p * 16 + q) * 16 + i) * 11;
        const float* uq = U3 + ((q * 16 + p) * 16 + i) * 11;
        #pragma unroll
        for (int k3 = 0; k3 < 11; ++k3)
            dst[k3 * KTSTRIDE] = h16(up[k3] + (p != q ? uq[k3] : 0.f));
        if (i == 0) {
            short* d0 = Bg + 11 * KTSTRIDE + (nt * 64 + lb) * 8;
            #pragma unroll
            for (int jj = 0; jj < 4; ++jj)
                d0[jj] = h16(U2[(p * 16 + q) * 4 + jj] + (p != q ? U2[(q * 16 + p) * 4 + jj] : 0.f));
            #pragma unroll
            for (int jj = 4; jj < 8; ++jj) d0[jj] = 0;
            short* d1 = Bg + 11 * KTSTRIDE + (nt * 64 + lb + 32) * 8;
            #pragma unroll
            for (int jj = 0; jj < 8; ++jj) d1[jj] = 0;
        }
    } else {
        #pragma unroll
        for (int k3 = 0; k3 < 11; ++k3) dst[k3 * KTSTRIDE] = 0;
        if (i == 0) {
            short* d0 = Bg + 11 * KTSTRIDE + (nt * 64 + lb) * 8;
            short* d1 = Bg + 11 * KTSTRIDE + (nt * 64 + lb + 32) * 8;
            #pragma unroll
            for (int jj = 0; jj < 8; ++jj) { d0[jj] = 0; d1[jj] = 0; }
        }
    }
}

// ---------------------------------------------------------------------------
// Main: 512-thread block = 8 waves = 2 nodes x 4 channel-groups. U (60 KB)
// staged once into LDS per block (wave-aligned global_load_lds), ONE barrier,
// then every wave free-runs: D^T[n,m] = Usym[n,k] . z[k,m] from ds_read_b128,
// register-only quadratic epilogue, no further synchronization.
// ---------------------------------------------------------------------------
__global__ __launch_bounds__(512, 4)
void symcon_main(const float* __restrict__ x, const float* __restrict__ y,
                 const float* __restrict__ U1, const float* __restrict__ W3,
                 const float* __restrict__ W2, const float* __restrict__ W1,
                 const short* __restrict__ Bg, float* __restrict__ out)
{
    __shared__ __align__(16) short Ul[NCHUNK * 8];   // 61440 B

    const int tid  = threadIdx.x;
    const int lane = tid & 63;
    const int wid  = tid >> 6;            // 0..7
    const int node = blockIdx.x * 2 + (wid >> 2);
    const int wr   = wid & 3;
    const int col  = lane & 31;
    const int h    = lane >> 5;
    const int m    = wr * 32 + col;       // channel this lane owns

    // ---- stage U into LDS: 3840 chunks = 60 wave-loads (8 waves x 7 + 4) ----
    #pragma unroll
    for (int jj = 0; jj < 7; ++jj) {
        const int c = ((jj * 8 + wid) << 6) + lane;
        gload16(Bg + c * 8, &Ul[c * 8]);
    }
    if (wid < 4) {
        const int c = ((56 + wid) << 6) + lane;
        gload16(Bg + c * 8, &Ul[c * 8]);
    }

    // ---- x row (16 floats) ----
    const float* xp = x + ((size_t)node * 128 + m) * 16;
    const v4f f0 = *reinterpret_cast<const v4f*>(xp);
    const v4f f1 = *reinterpret_cast<const v4f*>(xp + 4);
    const v4f f2 = *reinterpret_cast<const v4f*>(xp + 8);
    const v4f f3 = *reinterpret_cast<const v4f*>(xp + 12);

    // ---- species (argmax, first-max wins) ----
    int e = 0;
    {
        const float* yr = y + node * 10;
        float best = yr[0];
        #pragma unroll
        for (int s2 = 1; s2 < 10; ++s2) { const float v = yr[s2]; if (v > best) { best = v; e = s2; } }
    }

    // ---- U1 dot (lane-local) ----
    float u1dot;
    {
        const v4f u0 = *reinterpret_cast<const v4f*>(U1);
        const v4f u1 = *reinterpret_cast<const v4f*>(U1 + 4);
        const v4f u2 = *reinterpret_cast<const v4f*>(U1 + 8);
        const v4f u3 = *reinterpret_cast<const v4f*>(U1 + 12);
        const v4f d  = f0 * u0 + f1 * u1 + f2 * u2 + f3 * u3;
        u1dot = d[0] + d[1] + d[2] + d[3];
    }

    // ---- per-lane weights (e-dependent gather, coalesced 32-lane rows) ----
    float w3r[11], w2r[4];
    #pragma unroll
    for (int k = 0; k < 11; ++k) w3r[k] = W3[(e * 11 + k) * 128 + m];
    #pragma unroll
    for (int k = 0; k < 4; ++k)  w2r[k] = W2[(e * 4 + k) * 128 + m];
    const float w1v = W1[e * 128 + m];

    // ---- lane's x half as packed fp16 (RNE): z k-elements 8h..8h+7 ----
    const v4f lo = h ? f2 : f0;
    const v4f hi = h ? f3 : f1;
    const h2 xh0 = h2{(__fp16)lo[0], (__fp16)lo[1]};
    const h2 xh1 = h2{(__fp16)lo[2], (__fp16)lo[3]};
    const h2 xh2 = h2{(__fp16)hi[0], (__fp16)hi[1]};
    const h2 xh3 = h2{(__fp16)hi[2], (__fp16)hi[3]};

    __syncthreads();   // U staged (drains vmcnt); the ONLY barrier

    v16f a0 = {}, a1 = {}, a2 = {}, a3 = {}, a4 = {};

    // ---- K loop: 12 kt x 5 n-tiles; A from LDS, B built in-register ----
    const short* Up = Ul + lane * 8;
    #pragma unroll
    for (int kt = 0; kt < 12; ++kt) {
        const v8h u0 = *reinterpret_cast<const v8h*>(Up + (kt * NT + 0) * 512);
        const v8h u1 = *reinterpret_cast<const v8h*>(Up + (kt * NT + 1) * 512);
        const v8h u2 = *reinterpret_cast<const v8h*>(Up + (kt * NT + 2) * 512);
        const v8h u3 = *reinterpret_cast<const v8h*>(Up + (kt * NT + 3) * 512);
        const v8h u4 = *reinterpret_cast<const v8h*>(Up + (kt * NT + 4) * 512);
        v8h b;
        if (kt < 11) {
            const __fp16 w = (__fp16)w3r[kt];
            const h2 wh = h2{w, w};
            b = pack4(xh0 * wh, xh1 * wh, xh2 * wh, xh3 * wh);
        } else {
            const h2 z = {};
            const h2 p0 = h ? z : h2{(__fp16)w2r[0], (__fp16)w2r[1]};
            const h2 p1 = h ? z : h2{(__fp16)w2r[2], (__fp16)w2r[3]};
            b = pack4(p0, p1, z, z);
        }
        a0 = mfma_f16(u0, b, a0);
        a1 = mfma_f16(u1, b, a1);
        a2 = mfma_f16(u2, b, a2);
        a3 = mfma_f16(u3, b, a3);
        a4 = mfma_f16(u4, b, a4);
    }

    // ---- register-only epilogue: s = sum_n D[m,n] * x_p(n) * x_q(n) ----
    float s = epi<0>(a0, f0, f1, f2, f3, h)
            + epi<1>(a1, f0, f1, f2, f3, h)
            + epi<2>(a2, f0, f1, f2, f3, h)
            + epi<3>(a3, f0, f1, f2, f3, h)
            + epi<4>(a4, f0, f1, f2, f3, h);

    s += __shfl_xor(s, 32);   // combine h=0/h=1 n-halves (same m)

    if (h == 0)
        out[(size_t)node * 128 + m] = s + w1v * u1dot;
}

extern "C" void kernel_launch(void* const* d_in, const int* in_sizes, int n_in,
                              void* d_out, int out_size, void* d_ws, size_t ws_size,
                              hipStream_t stream) {
    const float* x  = (const float*)d_in[0];
    const float* y  = (const float*)d_in[1];
    const float* U3 = (const float*)d_in[2];
    const float* U2 = (const float*)d_in[3];
    const float* U1 = (const float*)d_in[4];
    const float* W3 = (const float*)d_in[5];
    const float* W2 = (const float*)d_in[6];
    const float* W1 = (const float*)d_in[7];
    short* Bg = (short*)d_ws;   // 12*2560 shorts = 60 KB fp16 Usym

    symcon_prep<<<10, 256, 0, stream>>>(U3, U2, Bg);
    symcon_main<<<1024, 512, 0, stream>>>(x, y, U1, W3, W2, W1, Bg, (float*)d_out);
}